// Round 4
// baseline (84.336 us; speedup 1.0000x reference)
//
#include <hip/hip_runtime.h>
#include <hip/hip_bf16.h>
#include <stdint.h>

// ---------------- problem constants ----------------
#define BATCH  4096
#define IN_DIM 1024
#define HS     1024
#define K_DIM  2048                 // IN + HS
#define N_DIM  4096                 // 4 gates * HS (gate-interleaved, see pack)
#define BK 64
#define NKT (K_DIM / BK)            // 32 K-tiles
#define HALF_BYTES 16384            // 128 rows x 64 cols x 2B
#define TPB_BYTES  (NKT * HALF_BYTES)   // bytes per 128-row panel, all K

typedef __bf16 bf16x8 __attribute__((ext_vector_type(8)));
typedef float  f32x4  __attribute__((ext_vector_type(4)));

// ---------------- helpers ----------------
__device__ __forceinline__ unsigned short f2bf(float f) {
    union { float f; uint32_t u; } a; a.f = f;
    uint32_t r = a.u + 0x7FFF + ((a.u >> 16) & 1);   // RNE
    return (unsigned short)(r >> 16);
}
__device__ __forceinline__ uint32_t pk2(float a, float b) {
    return (uint32_t)f2bf(a) | ((uint32_t)f2bf(b) << 16);
}

__device__ __forceinline__ void load16_lds(const void* g, void* l) {
    __builtin_amdgcn_global_load_lds(
        (const __attribute__((address_space(1))) uint32_t*)g,
        (__attribute__((address_space(3))) uint32_t*)(uintptr_t)l,
        16, 0, 0);
}
// stage one 16KB half-tile: 512 threads x 16B x 2 rounds
__device__ __forceinline__ void stage16k(const char* g, char* l, int wid, int lane) {
    load16_lds(g + wid * 1024 + lane * 16,        l + wid * 1024);
    load16_lds(g + 8192 + wid * 1024 + lane * 16, l + 8192 + wid * 1024);
}

__device__ __forceinline__ float sigf(float x)  { return 1.0f / (1.0f + __expf(-x)); }
__device__ __forceinline__ float tanhf_(float x){ return 1.0f - 2.0f / (__expf(2.0f * x) + 1.0f); }

#define BAR()   __builtin_amdgcn_s_barrier()
#define DSB()   __builtin_amdgcn_sched_barrier(0)
#define PRIO(x) __builtin_amdgcn_s_setprio(x)

__device__ __forceinline__ void rdA(bf16x8 (&d)[4], const char* base, int kb) {
    #pragma unroll
    for (int i = 0; i < 4; ++i) d[i] = *(const bf16x8*)(base + i * 2048 + kb);
}
__device__ __forceinline__ void rdB(bf16x8 (&d)[4], const char* base, int kb) {
    #pragma unroll
    for (int i = 0; i < 4; ++i) d[i] = *(const bf16x8*)(base + i * 2048 + kb);
}
__device__ __forceinline__ void mfma16(f32x4 (&acc)[8][4], int mh,
                                       const bf16x8 (&a)[4], const bf16x8 (&b)[4]) {
    #pragma unroll
    for (int i = 0; i < 4; ++i)
        #pragma unroll
        for (int j = 0; j < 4; ++j)
            acc[mh * 4 + i][j] = __builtin_amdgcn_mfma_f32_16x16x32_bf16(
                a[i], b[j], acc[mh * 4 + i][j], 0, 0, 0);
}

// ---------------- kernel 1: pack A=[x|h], B gate-INTERLEAVED ----------------
// Packed B column n' -> gate q=(n'>>4)&3, unit u=((n'>>6)<<4)|(n'&15), so the
// GEMM fragment (col = base + j*16 + fr) maps j -> gate, (bn,wn,fr) -> unit.
__global__ void pack_kernel(const float* __restrict__ x, const float* __restrict__ h,
                            const float* __restrict__ Wix, const float* __restrict__ Wfx,
                            const float* __restrict__ Wgx, const float* __restrict__ Wox,
                            const float* __restrict__ Wih, const float* __restrict__ Wfh,
                            const float* __restrict__ Wgh, const float* __restrict__ Woh,
                            uint4* __restrict__ Apk, uint4* __restrict__ Bpk)
{
    int t = blockIdx.x * blockDim.x + threadIdx.x;     // 0 .. 2M-1
    const int NCHUNK = (BATCH * K_DIM) / 8;            // 1,048,576 chunks / matrix
    bool isB = t >= NCHUNK;
    int ci = isB ? (t - NCHUNK) : t;

    int cb  = ci & 7;              // 16B chunk within row (8 bf16)
    int row = (ci >> 3) & 127;     // row within 128-row panel
    int kt  = (ci >> 10) & 31;     // K-tile
    int bt  = ci >> 15;            // 128-row panel index, 0..31

    // inverse swizzle: chunk cb of LDS row holds source chunk cb ^ (row&7)
    int k0 = kt * BK + ((cb ^ (row & 7)) << 3);        // source k element, %8==0
    int gr = bt * 128 + row;                           // global m or packed col n'

    const float* src;
    if (!isB) {
        src = (k0 < IN_DIM) ? (x + (size_t)gr * IN_DIM + k0)
                            : (h + (size_t)gr * HS + (k0 - IN_DIM));
    } else {
        int q = (gr >> 4) & 3;                         // gate
        int u = ((gr >> 6) << 4) | (gr & 15);          // unit
        const float* Wq = (k0 < IN_DIM)
            ? ((q == 0) ? Wix : (q == 1) ? Wfx : (q == 2) ? Wgx : Wox)
            : ((q == 0) ? Wih : (q == 1) ? Wfh : (q == 2) ? Wgh : Woh);
        int kk = (k0 < IN_DIM) ? k0 : (k0 - IN_DIM);
        src = Wq + (size_t)u * 1024 + kk;
    }
    float4 v0 = ((const float4*)src)[0];
    float4 v1 = ((const float4*)src)[1];
    uint4 o;
    o.x = pk2(v0.x, v0.y); o.y = pk2(v0.z, v0.w);
    o.z = pk2(v1.x, v1.y); o.w = pk2(v1.z, v1.w);
    (isB ? Bpk : Apk)[ci] = o;
}

// ---------------- kernel 2: fused GEMM + LSTM gates ----------------
// 256x256 tile, 8 waves (2Mx4N). Per-phase: {ds_reads feeding THIS phase's
// MFMA; 1 half-tile stage; MFMA cluster with COMPILER-inserted fine-grained
// lgkmcnt (no manual lgkmcnt(0) -- lets early MFMAs overlap late reads);
// barrier}. Counted vmcnt(4) once per K-tile at p3 (never 0 in steady state).
// Race proof: a wave's phase reads are consumed (compiler lgkm waits) before
// it reaches its phase-end barrier; any stage overwriting a region is issued
// >=2 barriers after the last read of that region; cooperative staging is
// jointly drained by per-wave counted vmcnt + barrier (uniform code).
__global__ void __launch_bounds__(512, 2)
gemm_kernel(const char* __restrict__ Apk, const char* __restrict__ Bpk,
            const float* __restrict__ c,
            const float* __restrict__ bix, const float* __restrict__ bfx,
            const float* __restrict__ bgx, const float* __restrict__ box_,
            const float* __restrict__ bih, const float* __restrict__ bfh,
            const float* __restrict__ bgh, const float* __restrict__ boh,
            float* __restrict__ out)
{
    __shared__ uint4 lds4[131072 / 16];                // 128 KiB
    char* lds = (char*)lds4;

    const int tid  = threadIdx.x;
    const int lane = tid & 63;
    const int wid  = tid >> 6;       // 0..7
    const int wm   = wid >> 2;       // 0..1
    const int wn   = wid & 3;        // 0..3
    const int fr   = lane & 15;
    const int kg   = lane >> 4;

    // XCD-aware bijective swizzle: 256 blocks, 8 XCDs, 32 blocks/XCD chunk
    const int phys = blockIdx.x;
    const int virt = (phys & 7) * 32 + (phys >> 3);
    const int bn   = virt & 15;
    const int bm   = virt >> 4;

    const char* gA = Apk + (size_t)(bm * 2) * TPB_BYTES;
    const char* gB = Bpk + (size_t)(bn * 2) * TPB_BYTES;

    // ds_read addressing (swizzle: k-byte ^ ((row&7)<<4); row%8 == fr%8)
    const int sw  = (fr & 7) << 4;
    const int kb0 = (kg * 16) ^ sw;                 // ks=0
    const int kb1 = (64 + kg * 16) ^ sw;            // ks=1
    const int aB  = wm * HALF_BYTES + fr * 128;     // A: half index == wm
    const int bB  = 32768 + (wn >> 1) * HALF_BYTES + ((wn & 1) * 64 + fr) * 128;

    f32x4 acc[8][4] = {};

    // ---- prologue: tile 0 (A0,A1,B0,B1) + tile 1 (B0,B1) ----
    stage16k(gA + (size_t)(0 * NKT + 0) * HALF_BYTES, lds + 0,     wid, lane);
    stage16k(gA + (size_t)(1 * NKT + 0) * HALF_BYTES, lds + 16384, wid, lane);
    stage16k(gB + (size_t)(0 * NKT + 0) * HALF_BYTES, lds + 32768, wid, lane);
    stage16k(gB + (size_t)(1 * NKT + 0) * HALF_BYTES, lds + 49152, wid, lane);
    stage16k(gB + (size_t)(0 * NKT + 1) * HALF_BYTES, lds + 65536 + 32768, wid, lane);
    stage16k(gB + (size_t)(1 * NKT + 1) * HALF_BYTES, lds + 65536 + 49152, wid, lane);
    asm volatile("s_waitcnt vmcnt(4)" ::: "memory");   // tile0 landed; tile1-B in flight
    BAR(); DSB();

    for (int kt = 0; kt < NKT; ++kt) {
        char* L  = lds + (kt & 1) * 65536;
        char* Ln = lds + ((kt & 1) ^ 1) * 65536;
        const bool s1 = (kt + 1 < NKT), s2 = (kt + 2 < NKT);
        bf16x8 aX[4], aY[4], b0[4], b1[4];

        // ---- phase 0: (mh0,ks0); stage A-h0(kt+1) ----
        rdA(aX, L + aB, kb0);
        rdB(b0, L + bB, kb0);
        if (s1) stage16k(gA + (size_t)(0 * NKT + kt + 1) * HALF_BYTES, Ln + 0, wid, lane);
        PRIO(1); mfma16(acc, 0, aX, b0); PRIO(0);
        BAR(); DSB();

        // ---- phase 1: (mh0,ks1); stage A-h1(kt+1) ----
        rdA(aY, L + aB, kb1);
        rdB(b1, L + bB, kb1);
        if (s1) stage16k(gA + (size_t)(1 * NKT + kt + 1) * HALF_BYTES, Ln + 16384, wid, lane);
        PRIO(1); mfma16(acc, 0, aY, b1); PRIO(0);
        BAR(); DSB();

        // ---- phase 2: (mh1,ks0); b0 from registers; stage B-h0(kt+2) ----
        rdA(aX, L + aB + 8192, kb0);
        if (s2) stage16k(gB + (size_t)(0 * NKT + kt + 2) * HALF_BYTES, L + 32768, wid, lane);
        PRIO(1); mfma16(acc, 1, aX, b0); PRIO(0);
        BAR(); DSB();

        // ---- phase 3: (mh1,ks1); b1 from registers; stage B-h1(kt+2);
        //      counted vmcnt AFTER the MFMA cluster, before the barrier ----
        rdA(aY, L + aB + 8192, kb1);
        if (s2) stage16k(gB + (size_t)(1 * NKT + kt + 2) * HALF_BYTES, L + 49152, wid, lane);
        PRIO(1); mfma16(acc, 1, aY, b1); PRIO(0);
        if (kt < NKT - 2) asm volatile("s_waitcnt vmcnt(4)" ::: "memory");
        else              asm volatile("s_waitcnt vmcnt(0)" ::: "memory");
        BAR(); DSB();
    }

    // ---- fused LSTM epilogue: lane holds all 4 gates of unit u, rows of acc
    const int u  = bn * 64 + wn * 16 + fr;             // unit 0..1023
    const int r0 = bm * 256 + wm * 128;                // batch row base
    const float bi = bix[u] + bih[u];
    const float bf = bfx[u] + bfh[u];
    const float bg = bgx[u] + bgh[u];
    const float bo = box_[u] + boh[u];
    float* hout = out;
    float* cout = out + (size_t)BATCH * HS;

    #pragma unroll
    for (int ai = 0; ai < 8; ++ai) {
        const int rowb = r0 + ai * 16 + kg * 4;
        #pragma unroll
        for (int r = 0; r < 4; ++r) {
            const size_t idx = (size_t)(rowb + r) * HS + u;
            float iv = sigf  (acc[ai][0][r] + bi);
            float fv = sigf  (acc[ai][1][r] + bf);
            float gv = tanhf_(acc[ai][2][r] + bg);
            float ov = sigf  (acc[ai][3][r] + bo);
            float cn = fv * c[idx] + iv * gv;
            hout[idx] = ov * tanhf_(cn);
            cout[idx] = cn;
        }
    }
}

// ---------------- launcher ----------------
extern "C" void kernel_launch(void* const* d_in, const int* in_sizes, int n_in,
                              void* d_out, int out_size, void* d_ws, size_t ws_size,
                              hipStream_t stream)
{
    const float* x   = (const float*)d_in[0];
    const float* h   = (const float*)d_in[1];
    const float* c   = (const float*)d_in[2];
    const float* Wix = (const float*)d_in[3];  const float* bix = (const float*)d_in[4];
    const float* Wfx = (const float*)d_in[5];  const float* bfx = (const float*)d_in[6];
    const float* Wgx = (const float*)d_in[7];  const float* bgx = (const float*)d_in[8];
    const float* Wox = (const float*)d_in[9];  const float* box_ = (const float*)d_in[10];
    const float* Wih = (const float*)d_in[11]; const float* bih = (const float*)d_in[12];
    const float* Wfh = (const float*)d_in[13]; const float* bfh = (const float*)d_in[14];
    const float* Wgh = (const float*)d_in[15]; const float* bgh = (const float*)d_in[16];
    const float* Woh = (const float*)d_in[17]; const float* boh = (const float*)d_in[18];

    char* ws = (char*)d_ws;
    uint4* Apk = (uint4*)ws;                                   // 16 MB
    uint4* Bpk = (uint4*)(ws + (size_t)16 * 1024 * 1024);      // 16 MB

    pack_kernel<<<8192, 256, 0, stream>>>(x, h, Wix, Wfx, Wgx, Wox,
                                          Wih, Wfh, Wgh, Woh, Apk, Bpk);
    gemm_kernel<<<256, 512, 0, stream>>>((const char*)Apk, (const char*)Bpk, c,
                                         bix, bfx, bgx, box_, bih, bfh, bgh, boh,
                                         (float*)d_out);
}

// Round 5
// 83.507 us; speedup vs baseline: 1.0099x; 1.0099x over previous
//
#include <hip/hip_runtime.h>
#include <hip/hip_bf16.h>
#include <stdint.h>

// ---------------- problem constants ----------------
#define BATCH  4096
#define IN_DIM 1024
#define HS     1024
#define K_DIM  2048                 // IN + HS
#define N_DIM  4096                 // 4 gates * HS (gate-interleaved, see pack)
#define BK 64
#define NKT (K_DIM / BK)            // 32 K-tiles
#define HALF_BYTES 16384            // 128 rows x 64 cols x 2B
#define TPB_BYTES  (NKT * HALF_BYTES)   // bytes per 128-row panel, all K

typedef __bf16 bf16x8 __attribute__((ext_vector_type(8)));
typedef float  f32x4  __attribute__((ext_vector_type(4)));

// ---------------- helpers ----------------
__device__ __forceinline__ unsigned short f2bf(float f) {
    union { float f; uint32_t u; } a; a.f = f;
    uint32_t r = a.u + 0x7FFF + ((a.u >> 16) & 1);   // RNE
    return (unsigned short)(r >> 16);
}
__device__ __forceinline__ uint32_t pk2(float a, float b) {
    return (uint32_t)f2bf(a) | ((uint32_t)f2bf(b) << 16);
}

__device__ __forceinline__ void load16_lds(const void* g, void* l) {
    __builtin_amdgcn_global_load_lds(
        (const __attribute__((address_space(1))) uint32_t*)g,
        (__attribute__((address_space(3))) uint32_t*)(uintptr_t)l,
        16, 0, 0);
}
// stage one 16KB half-tile: 512 threads x 16B x 2 rounds
__device__ __forceinline__ void stage16k(const char* g, char* l, int wid, int lane) {
    load16_lds(g + wid * 1024 + lane * 16,        l + wid * 1024);
    load16_lds(g + 8192 + wid * 1024 + lane * 16, l + 8192 + wid * 1024);
}

__device__ __forceinline__ float sigf(float x)  { return 1.0f / (1.0f + __expf(-x)); }
__device__ __forceinline__ float tanhf_(float x){ return 1.0f - 2.0f / (__expf(2.0f * x) + 1.0f); }

#define BAR()   __builtin_amdgcn_s_barrier()
#define PRIO(x) __builtin_amdgcn_s_setprio(x)

// 4 A-reads of one 32-row quad: d[mf*2+ks]
__device__ __forceinline__ void rdA4(bf16x8 (&d)[4], const char* base, int kb0, int kb1) {
    d[0] = *(const bf16x8*)(base + kb0);
    d[1] = *(const bf16x8*)(base + kb1);
    d[2] = *(const bf16x8*)(base + 2048 + kb0);
    d[3] = *(const bf16x8*)(base + 2048 + kb1);
}
// 8 B-reads of the full 64-col x 64-k wave B-slice: d[ks*4+j]
__device__ __forceinline__ void rdB8(bf16x8 (&d)[8], const char* base, int kb0, int kb1) {
    #pragma unroll
    for (int j = 0; j < 4; ++j) {
        d[j]     = *(const bf16x8*)(base + j * 2048 + kb0);
        d[4 + j] = *(const bf16x8*)(base + j * 2048 + kb1);
    }
}
// 16 MFMA for quadrant Q (rows [Q*32, Q*32+32) of the wave tile)
template<int Q>
__device__ __forceinline__ void mfq(f32x4 (&acc)[8][4], const bf16x8 (&a)[4],
                                    const bf16x8 (&b)[8]) {
    #pragma unroll
    for (int mf = 0; mf < 2; ++mf)
        #pragma unroll
        for (int ks = 0; ks < 2; ++ks)
            #pragma unroll
            for (int j = 0; j < 4; ++j)
                acc[2 * Q + mf][j] = __builtin_amdgcn_mfma_f32_16x16x32_bf16(
                    a[mf * 2 + ks], b[ks * 4 + j], acc[2 * Q + mf][j], 0, 0, 0);
}

// ---------------- kernel 1: pack A=[x|h], B gate-INTERLEAVED (unchanged) ----
__global__ void pack_kernel(const float* __restrict__ x, const float* __restrict__ h,
                            const float* __restrict__ Wix, const float* __restrict__ Wfx,
                            const float* __restrict__ Wgx, const float* __restrict__ Wox,
                            const float* __restrict__ Wih, const float* __restrict__ Wfh,
                            const float* __restrict__ Wgh, const float* __restrict__ Woh,
                            uint4* __restrict__ Apk, uint4* __restrict__ Bpk)
{
    int t = blockIdx.x * blockDim.x + threadIdx.x;     // 0 .. 2M-1
    const int NCHUNK = (BATCH * K_DIM) / 8;            // 1,048,576 chunks / matrix
    bool isB = t >= NCHUNK;
    int ci = isB ? (t - NCHUNK) : t;

    int cb  = ci & 7;              // 16B chunk within row (8 bf16)
    int row = (ci >> 3) & 127;     // row within 128-row panel
    int kt  = (ci >> 10) & 31;     // K-tile
    int bt  = ci >> 15;            // 128-row panel index, 0..31

    // inverse swizzle: chunk cb of LDS row holds source chunk cb ^ (row&7)
    int k0 = kt * BK + ((cb ^ (row & 7)) << 3);        // source k element, %8==0
    int gr = bt * 128 + row;                           // global m or packed col n'

    const float* src;
    if (!isB) {
        src = (k0 < IN_DIM) ? (x + (size_t)gr * IN_DIM + k0)
                            : (h + (size_t)gr * HS + (k0 - IN_DIM));
    } else {
        int q = (gr >> 4) & 3;                         // gate
        int u = ((gr >> 6) << 4) | (gr & 15);          // unit
        const float* Wq = (k0 < IN_DIM)
            ? ((q == 0) ? Wix : (q == 1) ? Wfx : (q == 2) ? Wgx : Wox)
            : ((q == 0) ? Wih : (q == 1) ? Wfh : (q == 2) ? Wgh : Woh);
        int kk = (k0 < IN_DIM) ? k0 : (k0 - IN_DIM);
        src = Wq + (size_t)u * 1024 + kk;
    }
    float4 v0 = ((const float4*)src)[0];
    float4 v1 = ((const float4*)src)[1];
    uint4 o;
    o.x = pk2(v0.x, v0.y); o.y = pk2(v0.z, v0.w);
    o.z = pk2(v1.x, v1.y); o.w = pk2(v1.z, v1.w);
    (isB ? Bpk : Apk)[ci] = o;
}

// ---------------- kernel 2: fused GEMM + LSTM gates ----------------
// 256x256 tile, 8 waves (2Mx4N), wave-tile 128x64, quadrant-phase schedule:
// per phase: [vmcnt if P0/P3] [1 stage (tile kt+2, modulo-wrapped, uniform)]
// [4 A-reads for NEXT phase (+8 B-reads for NEXT TILE at P0)] [16 MFMA on
// regs read >=1 phase ago; compiler inserts precise counted lgkm waits]
// [barrier]. B double-buffered in registers (bA_/bB_), A in aE/aO.
// vmcnt(4)@P0 guarantees B(kt+1) landed; vmcnt(6)@P3 guarantees A(kt+1).
// Staging wraps modulo NKT so counts stay uniform (no guards); the extra
// 2 re-staged tiles are read-unused.
__global__ void __launch_bounds__(512, 2)
gemm_kernel(const char* __restrict__ Apk, const char* __restrict__ Bpk,
            const float* __restrict__ c,
            const float* __restrict__ bix, const float* __restrict__ bfx,
            const float* __restrict__ bgx, const float* __restrict__ box_,
            const float* __restrict__ bih, const float* __restrict__ bfh,
            const float* __restrict__ bgh, const float* __restrict__ boh,
            float* __restrict__ out)
{
    __shared__ uint4 lds4[131072 / 16];                // 128 KiB
    char* lds = (char*)lds4;

    const int tid  = threadIdx.x;
    const int lane = tid & 63;
    const int wid  = tid >> 6;       // 0..7
    const int wm   = wid >> 2;       // 0..1
    const int wn   = wid & 3;        // 0..3
    const int fr   = lane & 15;
    const int kg   = lane >> 4;

    // XCD-aware bijective swizzle: 256 blocks, 8 XCDs, 32 blocks/XCD chunk
    const int phys = blockIdx.x;
    const int virt = (phys & 7) * 32 + (phys >> 3);
    const int bn   = virt & 15;
    const int bm   = virt >> 4;

    const char* gA = Apk + (size_t)(bm * 2) * TPB_BYTES;
    const char* gB = Bpk + (size_t)(bn * 2) * TPB_BYTES;

    // ds_read addressing (swizzle: k-byte ^ ((row&7)<<4); row%8 == fr%8)
    const int kb0   = (kg * 16) ^ ((fr & 7) << 4);
    const int kb1   = kb0 ^ 64;
    const int aBase = wm * 16384 + fr * 128;           // + q*4096 + mf*2048
    const int bBase = 32768 + wn * 8192 + fr * 128;    // + j*2048

    f32x4 acc[8][4] = {};
    bf16x8 aE[4], aO[4], bA_[8], bB_[8];

    // ---- prologue: tile0 (A0,A1,B0,B1) then tile1 (B0,B1,A0,A1) ----
    stage16k(gA + (size_t)(0 * NKT + 0) * HALF_BYTES, lds + 0,     wid, lane);
    stage16k(gA + (size_t)(1 * NKT + 0) * HALF_BYTES, lds + 16384, wid, lane);
    stage16k(gB + (size_t)(0 * NKT + 0) * HALF_BYTES, lds + 32768, wid, lane);
    stage16k(gB + (size_t)(1 * NKT + 0) * HALF_BYTES, lds + 49152, wid, lane);
    stage16k(gB + (size_t)(0 * NKT + 1) * HALF_BYTES, lds + 65536 + 32768, wid, lane);
    stage16k(gB + (size_t)(1 * NKT + 1) * HALF_BYTES, lds + 65536 + 49152, wid, lane);
    stage16k(gA + (size_t)(0 * NKT + 1) * HALF_BYTES, lds + 65536 + 0,     wid, lane);
    stage16k(gA + (size_t)(1 * NKT + 1) * HALF_BYTES, lds + 65536 + 16384, wid, lane);
    asm volatile("s_waitcnt vmcnt(8)" ::: "memory");   // tile0 landed; tile1 in flight
    BAR();
    rdB8(bA_, lds + bBase, kb0, kb1);                  // B(0) -> bCur
    rdA4(aE, lds + aBase, kb0, kb1);                   // A(0, q0)

    // one K-tile = 4 phases; BCUR consumed, BNXT loaded (next tile's B)
#define TILE(L, LN, KT2, BCUR, BNXT)                                          \
    { /* P0 */                                                                \
      asm volatile("s_waitcnt vmcnt(4)" ::: "memory");                        \
      stage16k(gB + (size_t)(0 * NKT + (KT2)) * HALF_BYTES, (L) + 32768, wid, lane); \
      rdA4(aO, (L) + aBase + 4096, kb0, kb1);                                 \
      rdB8(BNXT, (LN) + bBase, kb0, kb1);                                     \
      PRIO(1); mfq<0>(acc, aE, BCUR); PRIO(0); BAR();                         \
      /* P1 */                                                                \
      stage16k(gB + (size_t)(1 * NKT + (KT2)) * HALF_BYTES, (L) + 49152, wid, lane); \
      rdA4(aE, (L) + aBase + 8192, kb0, kb1);                                 \
      PRIO(1); mfq<1>(acc, aO, BCUR); PRIO(0); BAR();                         \
      /* P2 */                                                                \
      stage16k(gA + (size_t)(0 * NKT + (KT2)) * HALF_BYTES, (L) + 0, wid, lane); \
      rdA4(aO, (L) + aBase + 12288, kb0, kb1);                                \
      PRIO(1); mfq<2>(acc, aE, BCUR); PRIO(0); BAR();                         \
      /* P3 */                                                                \
      asm volatile("s_waitcnt vmcnt(6)" ::: "memory");                        \
      stage16k(gA + (size_t)(1 * NKT + (KT2)) * HALF_BYTES, (L) + 16384, wid, lane); \
      rdA4(aE, (LN) + aBase, kb0, kb1);                                       \
      PRIO(1); mfq<3>(acc, aO, BCUR); PRIO(0); BAR();                         \
    }

    for (int it = 0; it < NKT / 2; ++it) {
        const int k2e = (it * 2 + 2) & (NKT - 1);
        const int k2o = (it * 2 + 3) & (NKT - 1);
        TILE(lds,         lds + 65536, k2e, bA_, bB_);
        TILE(lds + 65536, lds,         k2o, bB_, bA_);
    }
#undef TILE

    // ---- fused LSTM epilogue: lane holds all 4 gates of unit u, rows of acc
    const int u  = bn * 64 + wn * 16 + fr;             // unit 0..1023
    const int r0 = bm * 256 + wm * 128;                // batch row base
    const float bi = bix[u] + bih[u];
    const float bf = bfx[u] + bfh[u];
    const float bg = bgx[u] + bgh[u];
    const float bo = box_[u] + boh[u];
    float* hout = out;
    float* cout = out + (size_t)BATCH * HS;

    #pragma unroll
    for (int ai = 0; ai < 8; ++ai) {
        const int rowb = r0 + ai * 16 + kg * 4;
        #pragma unroll
        for (int r = 0; r < 4; ++r) {
            const size_t idx = (size_t)(rowb + r) * HS + u;
            float iv = sigf  (acc[ai][0][r] + bi);
            float fv = sigf  (acc[ai][1][r] + bf);
            float gv = tanhf_(acc[ai][2][r] + bg);
            float ov = sigf  (acc[ai][3][r] + bo);
            float cn = fv * c[idx] + iv * gv;
            hout[idx] = ov * tanhf_(cn);
            cout[idx] = cn;
        }
    }
}

// ---------------- launcher ----------------
extern "C" void kernel_launch(void* const* d_in, const int* in_sizes, int n_in,
                              void* d_out, int out_size, void* d_ws, size_t ws_size,
                              hipStream_t stream)
{
    const float* x   = (const float*)d_in[0];
    const float* h   = (const float*)d_in[1];
    const float* c   = (const float*)d_in[2];
    const float* Wix = (const float*)d_in[3];  const float* bix = (const float*)d_in[4];
    const float* Wfx = (const float*)d_in[5];  const float* bfx = (const float*)d_in[6];
    const float* Wgx = (const float*)d_in[7];  const float* bgx = (const float*)d_in[8];
    const float* Wox = (const float*)d_in[9];  const float* box_ = (const float*)d_in[10];
    const float* Wih = (const float*)d_in[11]; const float* bih = (const float*)d_in[12];
    const float* Wfh = (const float*)d_in[13]; const float* bfh = (const float*)d_in[14];
    const float* Wgh = (const float*)d_in[15]; const float* bgh = (const float*)d_in[16];
    const float* Woh = (const float*)d_in[17]; const float* boh = (const float*)d_in[18];

    char* ws = (char*)d_ws;
    uint4* Apk = (uint4*)ws;                                   // 16 MB
    uint4* Bpk = (uint4*)(ws + (size_t)16 * 1024 * 1024);      // 16 MB

    pack_kernel<<<8192, 256, 0, stream>>>(x, h, Wix, Wfx, Wgx, Wox,
                                          Wih, Wfh, Wgh, Woh, Apk, Bpk);
    gemm_kernel<<<256, 512, 0, stream>>>((const char*)Apk, (const char*)Bpk, c,
                                         bix, bfx, bgx, box_, bih, bfh, bgh, boh,
                                         (float*)d_out);
}